// Round 1
// baseline (297.395 us; speedup 1.0000x reference)
//
#include <hip/hip_runtime.h>
#include <hip/hip_bf16.h>

typedef __hip_bfloat16 bf16;
typedef __attribute__((ext_vector_type(8))) short bf16x8;
typedef __attribute__((ext_vector_type(4))) float f32x4;

// Problem constants: x (L=1024, N=8, C=1024), H=16 heads, hd=64
#define LOGIT_MAX 4.6051702f   // log(1/0.01)

__device__ __forceinline__ float4 load4(const float* p) { return *(const float4*)p; }

__device__ __forceinline__ void store4bf(bf16* p, float4 v) {
    union { bf16 b[4]; uint2 u; } t;
    t.b[0] = __float2bfloat16(v.x); t.b[1] = __float2bfloat16(v.y);
    t.b[2] = __float2bfloat16(v.z); t.b[3] = __float2bfloat16(v.w);
    *(uint2*)p = t.u;
}

// async global->LDS, 16B/lane; lds base wave-uniform, lane i -> base + i*16B
__device__ __forceinline__ void async16(const bf16* g, const bf16* lds) {
    __builtin_amdgcn_global_load_lds(
        (const __attribute__((address_space(1))) void*)g,
        (__attribute__((address_space(3))) void*)lds, 16, 0, 0);
}

// raw barrier with compiler memory fence on both sides (no vmcnt(0) drain)
__device__ __forceinline__ void wg_barrier() {
    asm volatile("" ::: "memory");
    __builtin_amdgcn_s_barrier();
    asm volatile("" ::: "memory");
}
#define VMCNT(n) asm volatile("s_waitcnt vmcnt(" #n ")" ::: "memory")

// ---------------------------------------------------------------------------
// Kernel 0: dtype detection (1 = fp32 inputs, 0 = bf16 inputs).
// ---------------------------------------------------------------------------
__global__ void detect_kernel(const unsigned short* __restrict__ x, int* __restrict__ flag)
{
    __shared__ int cnt;
    if (threadIdx.x == 0) cnt = 0;
    __syncthreads();
    int c = 0;
    for (int i = threadIdx.x; i < 4096; i += 256) {
        const unsigned e = (x[i] >> 7) & 0xFF;
        if (e >= 0x90) c++;
    }
    atomicAdd(&cnt, c);
    __syncthreads();
    if (threadIdx.x == 0) *flag = (cnt > 64) ? 1 : 0;
}

// ---------------------------------------------------------------------------
// Kernel 0b (merged prep): small conversions -> fp32 ws (block 0), and in
// fp32 mode bf16 ws copies of x / in_proj_weight / out_w (all blocks).
// smallf: [0,3072) in_proj_bias, [3072,4096) out_b,
//         [4096,4112) exp(min(ls,MAX)), [4112,4128) head_scale.
// ---------------------------------------------------------------------------
__global__ __launch_bounds__(256) void prep_kernel(
    const int* __restrict__ flag,
    const void* __restrict__ x, const void* __restrict__ w_in, const void* __restrict__ out_w,
    const void* __restrict__ b_in, const void* __restrict__ out_b,
    const void* __restrict__ ls, const void* __restrict__ hs,
    bf16* __restrict__ xb, bf16* __restrict__ wb, bf16* __restrict__ owb,
    float* __restrict__ smallf)
{
    const int f = *flag;
    if (blockIdx.x == 0) {
        for (int idx = threadIdx.x; idx < 4128; idx += 256) {
            float v;
            if (f) {
                if (idx < 3072)      v = ((const float*)b_in)[idx];
                else if (idx < 4096) v = ((const float*)out_b)[idx - 3072];
                else if (idx < 4112) v = expf(fminf(((const float*)ls)[idx - 4096], LOGIT_MAX));
                else                 v = ((const float*)hs)[idx - 4112];
            } else {
                if (idx < 3072)      v = __bfloat162float(((const bf16*)b_in)[idx]);
                else if (idx < 4096) v = __bfloat162float(((const bf16*)out_b)[idx - 3072]);
                else if (idx < 4112) v = expf(fminf(__bfloat162float(((const bf16*)ls)[idx - 4096]), LOGIT_MAX));
                else                 v = __bfloat162float(((const bf16*)hs)[idx - 4112]);
            }
            smallf[idx] = v;
        }
    }
    if (f != 1) return;
    const size_t NX = 8388608, NW = 3145728, NO = 1048576;
    const size_t t0   = ((size_t)blockIdx.x * 256 + threadIdx.x) * 4;
    const size_t step = (size_t)gridDim.x * 256 * 4;
    for (size_t i = t0; i < NX; i += step) store4bf(xb + i, load4((const float*)x + i));
    for (size_t i = t0; i < NW; i += step) store4bf(wb + i, load4((const float*)w_in + i));
    for (size_t i = t0; i < NO; i += step) store4bf(owb + i, load4((const float*)out_w + i));
}

// ---------------------------------------------------------------------------
// Pipelined GEMM main loop: C_tile[128x256] += A[128xK] . B[256xK]^T, K=1024.
// 8 waves (2M x 4N), per-wave 64x64 output (acc 4x4 of 16x16 frags).
// LDS: double-buffered, split into k-half "planes":
//   Ab[buf][kh][128][32], Bb[buf][kh][256][32]  (96 KB total)
// Chunk swizzle within a 32-col plane: stored chunk c holds global chunk
// c ^ ((row>>1)&3); read side applies the same XOR -> <=2-way bank conflict.
// Schedule per K-tile t (c = t&1), 2 phases (kh = 0,1):
//   phase kh: STAGE plane kh of tile t+1 -> buf[c^1]   (3 global_load_lds)
//             s_waitcnt vmcnt(6)   -- plane kh of tile t (issued 2 phases ago)
//             s_barrier            -- cross-wave visibility
//             8 ds_read_b128 -> setprio(1) 16 MFMA setprio(0)
// vmcnt counted (never 0 in loop): exactly the 2 newest plane-sets stay in
// flight. WAR safety: stages at (t,p) write buf[c^1] plane p whose last
// readers all completed before the barrier my wave already passed.
// ---------------------------------------------------------------------------
__device__ __forceinline__ void mfma_mainloop_128x256(
    const bf16* __restrict__ A, const bf16* __restrict__ B,
    int row0, int col0, bf16* Ab, bf16* Bb, f32x4 (&acc)[4][4])
{
    const int tid  = threadIdx.x;
    const int w    = tid >> 6;
    const int lane = tid & 63;
    const int l16  = lane & 15, quad = lane >> 4;
    const int wr   = w >> 2, wc = w & 3;
    // staging: thread -> (row = tid>>2, chunk = tid&3), source pre-swizzled
    const int srow   = tid >> 2;
    const int schunk = (((tid & 3) ^ ((tid >> 3) & 3)) << 3);
    const bf16* Asrc  = A + (size_t)(row0 + srow) * 1024 + schunk;
    const bf16* Bsrc0 = B + (size_t)(col0 + srow) * 1024 + schunk;
    const bf16* Bsrc1 = B + (size_t)(col0 + 128 + srow) * 1024 + schunk;
    bf16* AW = Ab + w * 512;   // wave-uniform LDS stage bases (lane*16B added by HW)
    bf16* BW = Bb + w * 512;

#define STAGE(bufv, khv, kc) do {                                          \
    const int _o = (kc) + (khv) * 32;                                      \
    async16(Asrc  + _o, AW + ((bufv) * 2 + (khv)) * 4096);                 \
    async16(Bsrc0 + _o, BW + ((bufv) * 2 + (khv)) * 8192);                 \
    async16(Bsrc1 + _o, BW + ((bufv) * 2 + (khv)) * 8192 + 4096);          \
} while (0)

#define COMPUTE(bufv, khv) do {                                            \
    const bf16* Ap = Ab + ((bufv) * 2 + (khv)) * 4096;                     \
    const bf16* Bp = Bb + ((bufv) * 2 + (khv)) * 8192;                     \
    bf16x8 af[4], bfr[4];                                                  \
    _Pragma("unroll")                                                      \
    for (int mt = 0; mt < 4; mt++) {                                       \
        const int r = wr * 64 + mt * 16 + l16;                             \
        af[mt] = *(const bf16x8*)&Ap[r * 32 + ((quad ^ ((r >> 1) & 3)) << 3)]; \
    }                                                                      \
    _Pragma("unroll")                                                      \
    for (int nt = 0; nt < 4; nt++) {                                       \
        const int r = wc * 64 + nt * 16 + l16;                             \
        bfr[nt] = *(const bf16x8*)&Bp[r * 32 + ((quad ^ ((r >> 1) & 3)) << 3)]; \
    }                                                                      \
    __builtin_amdgcn_s_setprio(1);                                         \
    _Pragma("unroll")                                                      \
    for (int mt = 0; mt < 4; mt++)                                         \
        _Pragma("unroll")                                                  \
        for (int nt = 0; nt < 4; nt++)                                     \
            acc[mt][nt] = __builtin_amdgcn_mfma_f32_16x16x32_bf16(af[mt], bfr[nt], acc[mt][nt], 0, 0, 0); \
    __builtin_amdgcn_s_setprio(0);                                         \
} while (0)

    // prologue: tile 0, both planes (6 loads in flight)
    STAGE(0, 0, 0);
    STAGE(0, 1, 0);
#pragma unroll 1
    for (int t = 0; t < 15; ++t) {
        const int c = t & 1;
        STAGE(c ^ 1, 0, (t + 1) * 64);
        VMCNT(6); wg_barrier();
        COMPUTE(c, 0);
        STAGE(c ^ 1, 1, (t + 1) * 64);
        VMCNT(6); wg_barrier();
        COMPUTE(c, 1);
    }
    // tail: t = 15 (buf 1), nothing left to stage
    VMCNT(3); wg_barrier();
    COMPUTE(1, 0);
    VMCNT(0); wg_barrier();
    COMPUTE(1, 1);
#undef STAGE
#undef COMPUTE
}

// ---------------------------------------------------------------------------
// Kernel 1: MFMA QKV projection, pipelined 128x256 tile, fused q/k L2-norm.
// C[8192x3072] = X . W^T; grid 768 blocks (= 3/CU exactly), 512 threads.
// ---------------------------------------------------------------------------
__global__ __launch_bounds__(512, 2) void qkv_gemm_mfma_kernel(
    const int* __restrict__ flag,
    const bf16* __restrict__ Xws, const bf16* __restrict__ Wws,
    const bf16* __restrict__ Xdir, const bf16* __restrict__ Wdir,
    const float* __restrict__ bias_f,
    bf16* __restrict__ q, bf16* __restrict__ k, bf16* __restrict__ vt)
{
    const bf16* X = (*flag) ? Xws : Xdir;
    const bf16* W = (*flag) ? Wws : Wdir;
    __shared__ bf16 Ab[2 * 2 * 4096];   // 32 KB
    __shared__ bf16 Bb[2 * 2 * 8192];   // 64 KB

    // XCD-bijective swizzle (768 % 8 == 0): all col-tiles of 8 row-panels / XCD
    const int bid = blockIdx.x;
    const int wg  = (bid & 7) * 96 + (bid >> 3);
    const int bx  = wg % 12, by = wg / 12;
    const int row0 = by * 128;
    const int col0 = bx * 256;

    f32x4 acc[4][4] = {};
    mfma_mainloop_128x256(X, W, row0, col0, Ab, Bb, acc);

    const int tid  = threadIdx.x;
    const int w    = tid >> 6;
    const int lane = tid & 63;
    const int l16  = lane & 15, quad = lane >> 4;
    const int wr   = w >> 2, wc = w & 3;

    const int cbase = col0 + wc * 64;          // wave-uniform, spans one head
    const int part  = cbase >> 10;
    const int h     = (cbase & 1023) >> 6;
    float bias[4];
#pragma unroll
    for (int nt = 0; nt < 4; nt++) bias[nt] = bias_f[cbase + nt * 16 + l16];

    if (part < 2) {
        bf16* dst0 = (part == 0) ? q : k;
#pragma unroll
        for (int mt = 0; mt < 4; mt++) {
#pragma unroll
            for (int rg = 0; rg < 4; rg++) {
                const int r = row0 + wr * 64 + mt * 16 + quad * 4 + rg;
                const int l = r >> 3, nn = r & 7;
                float val[4]; float ss = 0.f;
#pragma unroll
                for (int nt = 0; nt < 4; nt++) {
                    val[nt] = acc[mt][nt][rg] + bias[nt];
                    ss += val[nt] * val[nt];
                }
                ss += __shfl_xor(ss, 1); ss += __shfl_xor(ss, 2);
                ss += __shfl_xor(ss, 4); ss += __shfl_xor(ss, 8);
                const float inv = 1.f / fmaxf(sqrtf(ss), 1e-12f);
                bf16* dp = dst0 + ((size_t)((nn * 16 + h) * 1024 + l)) * 64;
#pragma unroll
                for (int nt = 0; nt < 4; nt++)
                    dp[nt * 16 + l16] = __float2bfloat16(val[nt] * inv);
            }
        }
    } else {
#pragma unroll
        for (int mt = 0; mt < 4; mt++) {
#pragma unroll
            for (int rg = 0; rg < 4; rg++) {
                const int r = row0 + wr * 64 + mt * 16 + quad * 4 + rg;
                const int l = r >> 3, nn = r & 7;
#pragma unroll
                for (int nt = 0; nt < 4; nt++) {
                    const int d = nt * 16 + l16;
                    vt[((size_t)((nn * 16 + h) * 64 + d)) * 1024 + l] =
                        __float2bfloat16(acc[mt][nt][rg] + bias[nt]);
                }
            }
        }
    }
}

// ---------------------------------------------------------------------------
// Kernel 3: MFMA flash attention v2 + XCD swizzle (unchanged).
// ---------------------------------------------------------------------------
__global__ __launch_bounds__(256, 4) void attn_mfma_kernel(
    const bf16* __restrict__ q, const bf16* __restrict__ k,
    const bf16* __restrict__ vt, const float* __restrict__ scale_f,
    bf16* __restrict__ o)
{
    __shared__ bf16 K_lds[64][64];
    __shared__ bf16 Vt_lds[64][64];
    __shared__ bf16 P_lds[4][32][72];
    __shared__ float l_lds[4][32];

    const int bid  = blockIdx.x;
    const int qt   = bid >> 7;         // 0..7  (slow index)
    const int nh   = bid & 127;        // fast index -> XCD = nh & 7
    const int h    = nh & 15;
    const int n    = nh >> 4;
    const int tid  = threadIdx.x;
    const int w    = tid >> 6;
    const int lane = tid & 63;
    const int l16  = lane & 15;
    const int quad = lane >> 4;

    const size_t base = (size_t)nh * (1024 * 64);
    const float ls   = scale_f[4096 + h];
    const float hs   = scale_f[4112 + h];
    const float lsl2 = ls * 1.4426950408889634f;

    bf16x8 qf[2][2];
#pragma unroll
    for (int u = 0; u < 2; u++) {
        const int qrow = qt * 128 + w * 32 + u * 16 + l16;
        const bf16* qp = q + base + (size_t)qrow * 64 + quad * 8;
        qf[u][0] = *(const bf16x8*)qp;
        qf[u][1] = *(const bf16x8*)(qp + 32);
    }

    f32x4 o_acc[2][4] = {};
    float l_part[2] = {0.f, 0.f};

    const int sr = lane >> 3;
    const int sc = lane & 7;

    for (int j0 = 0; j0 < 1024; j0 += 64) {
        __syncthreads();
#pragma unroll
        for (int half = 0; half < 2; half++) {
            const int br  = w * 16 + half * 8;
            const int row = br + sr;
            const int cg  = sc ^ (row & 7);
            async16(k  + base + (size_t)(j0 + row) * 64 + cg * 8, &K_lds[br][0]);
            async16(vt + base + (size_t)row * 1024 + j0 + cg * 8, &Vt_lds[br][0]);
        }
        __syncthreads();

        f32x4 s8[2][4];
#pragma unroll
        for (int s = 0; s < 4; s++) {
            const int krow = s * 16 + l16;
            const int swz  = krow & 7;
            const bf16x8 kf0 = *(const bf16x8*)&K_lds[krow][(quad ^ swz) * 8];
            const bf16x8 kf1 = *(const bf16x8*)&K_lds[krow][((quad + 4) ^ swz) * 8];
#pragma unroll
            for (int u = 0; u < 2; u++) {
                f32x4 a = {};
                a = __builtin_amdgcn_mfma_f32_16x16x32_bf16(kf0, qf[u][0], a, 0, 0, 0);
                a = __builtin_amdgcn_mfma_f32_16x16x32_bf16(kf1, qf[u][1], a, 0, 0, 0);
                s8[u][s] = a;
            }
        }

#pragma unroll
        for (int u = 0; u < 2; u++) {
#pragma unroll
            for (int s = 0; s < 4; s++) {
                union { bf16 b[4]; uint2 uu; } pk;
                float sum = 0.f;
#pragma unroll
                for (int r = 0; r < 4; r++) {
                    const float p = exp2f(fmaf(s8[u][s][r], lsl2, -lsl2));
                    pk.b[r] = __float2bfloat16(p);
                    sum += p;
                }
                l_part[u] += sum;
                *(uint2*)&P_lds[w][u * 16 + l16][s * 16 + quad * 4] = pk.uu;
            }
        }

        bf16x8 pf[2][2];
#pragma unroll
        for (int u = 0; u < 2; u++) {
            pf[u][0] = *(const bf16x8*)&P_lds[w][u * 16 + l16][quad * 8];
            pf[u][1] = *(const bf16x8*)&P_lds[w][u * 16 + l16][32 + quad * 8];
        }
#pragma unroll
        for (int ds = 0; ds < 4; ds++) {
            const int vrow = ds * 16 + l16;
            const int swz  = vrow & 7;
            const bf16x8 vf0 = *(const bf16x8*)&Vt_lds[vrow][(quad ^ swz) * 8];
            const bf16x8 vf1 = *(const bf16x8*)&Vt_lds[vrow][((quad + 4) ^ swz) * 8];
#pragma unroll
            for (int u = 0; u < 2; u++) {
                o_acc[u][ds] = __builtin_amdgcn_mfma_f32_16x16x32_bf16(pf[u][0], vf0, o_acc[u][ds], 0, 0, 0);
                o_acc[u][ds] = __builtin_amdgcn_mfma_f32_16x16x32_bf16(pf[u][1], vf1, o_acc[u][ds], 0, 0, 0);
            }
        }
    }

#pragma unroll
    for (int u = 0; u < 2; u++) {
        float v = l_part[u];
        v += __shfl_xor(v, 16);
        v += __shfl_xor(v, 32);
        l_lds[w][u * 16 + l16] = v;
    }

#pragma unroll
    for (int u = 0; u < 2; u++) {
#pragma unroll
        for (int r = 0; r < 4; r++) {
            const float inv = hs / l_lds[w][u * 16 + quad * 4 + r];
            const int row_l = qt * 128 + w * 32 + u * 16 + quad * 4 + r;
            bf16* dst = o + ((size_t)row_l * 8 + n) * 1024 + h * 64 + l16;
#pragma unroll
            for (int ds = 0; ds < 4; ds++)
                dst[ds * 16] = __float2bfloat16(o_acc[u][ds][r] * inv);
        }
    }
}

// ---------------------------------------------------------------------------
// Kernel 4: MFMA out projection, pipelined 128x256 tile, single launch.
// out[8192x1024] = A . W^T + b; grid 256 blocks (= 1/CU exactly).
// ---------------------------------------------------------------------------
__global__ __launch_bounds__(512, 2) void out_gemm_mfma_kernel(
    const int* __restrict__ flag,
    const bf16* __restrict__ A,
    const bf16* __restrict__ Bws, const bf16* __restrict__ Bdir,
    const float* __restrict__ bias_f,
    float* __restrict__ outf, bf16* __restrict__ outb)
{
    const int f = *flag;
    const bf16* B = f ? Bws : Bdir;
    __shared__ bf16 Ab[2 * 2 * 4096];
    __shared__ bf16 Bb[2 * 2 * 8192];

    const int bid = blockIdx.x;
    const int wg  = (bid & 7) * 32 + (bid >> 3);
    const int bx  = wg & 3, by = wg >> 2;
    const int row0 = by * 128;
    const int col0 = bx * 256;

    f32x4 acc[4][4] = {};
    mfma_mainloop_128x256(A, B, row0, col0, Ab, Bb, acc);

    const int tid  = threadIdx.x;
    const int w    = tid >> 6;
    const int lane = tid & 63;
    const int l16  = lane & 15, quad = lane >> 4;
    const int wr   = w >> 2, wc = w & 3;

#pragma unroll
    for (int mt = 0; mt < 4; mt++) {
        const int rbase = row0 + wr * 64 + mt * 16 + quad * 4;
#pragma unroll
        for (int nt = 0; nt < 4; nt++) {
            const int c = col0 + wc * 64 + nt * 16 + l16;
            const float bias = bias_f[c];
#pragma unroll
            for (int rg = 0; rg < 4; rg++) {
                const float v = acc[mt][nt][rg] + bias;
                const size_t idx = (size_t)(rbase + rg) * 1024 + c;
                if (f) outf[idx] = v; else outb[idx] = __float2bfloat16(v);
            }
        }
    }
}

// ---------------------------------------------------------------------------
extern "C" void kernel_launch(void* const* d_in, const int* in_sizes, int n_in,
                              void* d_out, int out_size, void* d_ws, size_t ws_size,
                              hipStream_t stream)
{
    const size_t SEG = (size_t)8 * 16 * 1024 * 64;   // 8388608 elems
    bf16* qn  = (bf16*)d_ws;
    bf16* kn  = qn + SEG;
    bf16* vt  = kn + SEG;
    bf16* ow  = vt + SEG;
    bf16* xb  = ow + SEG;                  // bf16 copy of x (fp32 mode)
    bf16* wb  = xb + SEG;                  // bf16 copy of in_proj_weight
    bf16* owb = wb + 3145728;              // bf16 copy of out_w
    float* smallf = (float*)(owb + 1048576);   // 4128 floats
    int*   flag   = (int*)(smallf + 4128);

    detect_kernel<<<1, 256, 0, stream>>>((const unsigned short*)d_in[0], flag);

    prep_kernel<<<4096, 256, 0, stream>>>(flag,
        d_in[0], d_in[1], d_in[5], d_in[2], d_in[6], d_in[3], d_in[4],
        xb, wb, owb, smallf);

    // 1) qkv projection (pipelined MFMA, 128x256 tile) + fused q/k L2-normalize
    qkv_gemm_mfma_kernel<<<dim3(768), 512, 0, stream>>>(
        flag, xb, wb, (const bf16*)d_in[0], (const bf16*)d_in[1], smallf, qn, kn, vt);

    // 2) flash attention v2 (MFMA, fixed-max softmax, XCD-local nh)
    attn_mfma_kernel<<<dim3(128 * 8), 256, 0, stream>>>(qn, kn, vt, smallf, ow);

    // 3) out projection (pipelined MFMA, 128x256 tile), single launch
    out_gemm_mfma_kernel<<<dim3(256), 512, 0, stream>>>(
        flag, ow, owb, (const bf16*)d_in[5], smallf + 3072,
        (float*)d_out, (bf16*)d_out);
}

// Round 2
// 295.241 us; speedup vs baseline: 1.0073x; 1.0073x over previous
//
#include <hip/hip_runtime.h>
#include <hip/hip_bf16.h>

typedef __hip_bfloat16 bf16;
typedef __attribute__((ext_vector_type(8))) short bf16x8;
typedef __attribute__((ext_vector_type(4))) float f32x4;

// Problem constants: x (L=1024, N=8, C=1024), H=16 heads, hd=64
#define LOGIT_MAX 4.6051702f   // log(1/0.01)

__device__ __forceinline__ float4 load4(const float* p) { return *(const float4*)p; }

__device__ __forceinline__ void store4bf(bf16* p, float4 v) {
    union { bf16 b[4]; uint2 u; } t;
    t.b[0] = __float2bfloat16(v.x); t.b[1] = __float2bfloat16(v.y);
    t.b[2] = __float2bfloat16(v.z); t.b[3] = __float2bfloat16(v.w);
    *(uint2*)p = t.u;
}

// async global->LDS, 16B/lane; lds base wave-uniform, lane i -> base + i*16B
__device__ __forceinline__ void async16(const bf16* g, const bf16* lds) {
    __builtin_amdgcn_global_load_lds(
        (const __attribute__((address_space(1))) void*)g,
        (__attribute__((address_space(3))) void*)lds, 16, 0, 0);
}

// raw barrier with compiler memory fence on both sides (no vmcnt(0) drain)
__device__ __forceinline__ void wg_barrier() {
    asm volatile("" ::: "memory");
    __builtin_amdgcn_s_barrier();
    asm volatile("" ::: "memory");
}
#define S_WAITCNT_VM(n) asm volatile("s_waitcnt vmcnt(" #n ")" ::: "memory")
#define VMCNT(n) S_WAITCNT_VM(n)

// ---------------------------------------------------------------------------
// Kernel 0: dtype detection (1 = fp32 inputs, 0 = bf16 inputs).
// ---------------------------------------------------------------------------
__global__ void detect_kernel(const unsigned short* __restrict__ x, int* __restrict__ flag)
{
    __shared__ int cnt;
    if (threadIdx.x == 0) cnt = 0;
    __syncthreads();
    int c = 0;
    for (int i = threadIdx.x; i < 4096; i += 256) {
        const unsigned e = (x[i] >> 7) & 0xFF;
        if (e >= 0x90) c++;
    }
    atomicAdd(&cnt, c);
    __syncthreads();
    if (threadIdx.x == 0) *flag = (cnt > 64) ? 1 : 0;
}

// ---------------------------------------------------------------------------
// Kernel 0b (merged prep): small conversions -> fp32 ws (block 0), and in
// fp32 mode bf16 ws copies of x / in_proj_weight / out_w (all blocks).
// smallf: [0,3072) in_proj_bias, [3072,4096) out_b,
//         [4096,4112) exp(min(ls,MAX)), [4112,4128) head_scale.
// ---------------------------------------------------------------------------
__global__ __launch_bounds__(256) void prep_kernel(
    const int* __restrict__ flag,
    const void* __restrict__ x, const void* __restrict__ w_in, const void* __restrict__ out_w,
    const void* __restrict__ b_in, const void* __restrict__ out_b,
    const void* __restrict__ ls, const void* __restrict__ hs,
    bf16* __restrict__ xb, bf16* __restrict__ wb, bf16* __restrict__ owb,
    float* __restrict__ smallf)
{
    const int f = *flag;
    if (blockIdx.x == 0) {
        for (int idx = threadIdx.x; idx < 4128; idx += 256) {
            float v;
            if (f) {
                if (idx < 3072)      v = ((const float*)b_in)[idx];
                else if (idx < 4096) v = ((const float*)out_b)[idx - 3072];
                else if (idx < 4112) v = expf(fminf(((const float*)ls)[idx - 4096], LOGIT_MAX));
                else                 v = ((const float*)hs)[idx - 4112];
            } else {
                if (idx < 3072)      v = __bfloat162float(((const bf16*)b_in)[idx]);
                else if (idx < 4096) v = __bfloat162float(((const bf16*)out_b)[idx - 3072]);
                else if (idx < 4112) v = expf(fminf(__bfloat162float(((const bf16*)ls)[idx - 4096]), LOGIT_MAX));
                else                 v = __bfloat162float(((const bf16*)hs)[idx - 4112]);
            }
            smallf[idx] = v;
        }
    }
    if (f != 1) return;
    const size_t NX = 8388608, NW = 3145728, NO = 1048576;
    const size_t t0   = ((size_t)blockIdx.x * 256 + threadIdx.x) * 4;
    const size_t step = (size_t)gridDim.x * 256 * 4;
    for (size_t i = t0; i < NX; i += step) store4bf(xb + i, load4((const float*)x + i));
    for (size_t i = t0; i < NW; i += step) store4bf(wb + i, load4((const float*)w_in + i));
    for (size_t i = t0; i < NO; i += step) store4bf(owb + i, load4((const float*)out_w + i));
}

// ---------------------------------------------------------------------------
// Pipelined GEMM main loop: C_tile[128x256] += A[128xK] . B[256xK]^T, K=1024.
// 8 waves (2M x 4N), per-wave 64x64 output (acc 4x4 of 16x16 frags).
// LDS: TRIPLE-buffered k-half "planes" (prefetch distance 4 phases):
//   Ab[3][2][128][32], Bb[3][2][256][32]  (144 KB total)
// Chunk swizzle within a 32-col plane: stored chunk c holds global chunk
// c ^ ((row>>1)&3); read side applies the same XOR -> <=2-way conflict (free).
// Phase P = 2t + kh consumes tile t (buf t%3) plane kh and stages the plane
// for phase P+4 (tile t+2, buf (t+2)%3, same kh):
//   STAGE(3 x global_load_lds) ; s_waitcnt vmcnt(12) ; s_barrier ;
//   8 ds_read_b128 ; setprio(1) 16 MFMA setprio(0)
// vmcnt(12) = 4 in-flight stages x 3 loads -> the plane staged 4 phases ago
// has landed. WAR: a slot consumed at phase P is re-staged at P+2 (its
// readers all retired their ds_reads before passing barrier P+1, which the
// staging wave has also passed). Epilogue drains 12 -> 9 -> 6 -> 3 -> 0.
// ---------------------------------------------------------------------------
__device__ __forceinline__ void mfma_mainloop_128x256(
    const bf16* __restrict__ A, const bf16* __restrict__ B,
    int row0, int col0, bf16* Ab, bf16* Bb, f32x4 (&acc)[4][4])
{
    const int tid  = threadIdx.x;
    const int w    = tid >> 6;
    const int lane = tid & 63;
    const int l16  = lane & 15, quad = lane >> 4;
    const int wr   = w >> 2, wc = w & 3;
    // staging: thread -> (row = tid>>2, chunk = tid&3), source pre-swizzled
    const int srow   = tid >> 2;
    const int schunk = (((tid & 3) ^ ((tid >> 3) & 3)) << 3);
    const bf16* Asrc  = A + (size_t)(row0 + srow) * 1024 + schunk;
    const bf16* Bsrc0 = B + (size_t)(col0 + srow) * 1024 + schunk;
    const bf16* Bsrc1 = B + (size_t)(col0 + 128 + srow) * 1024 + schunk;
    bf16* AW = Ab + w * 512;   // wave-uniform LDS stage bases (lane*16B added by HW)
    bf16* BW = Bb + w * 512;

#define STAGE(bufv, khv, koff) do {                                        \
    async16(Asrc  + (koff), AW + ((bufv) * 2 + (khv)) * 4096);             \
    async16(Bsrc0 + (koff), BW + ((bufv) * 2 + (khv)) * 8192);             \
    async16(Bsrc1 + (koff), BW + ((bufv) * 2 + (khv)) * 8192 + 4096);      \
} while (0)

#define COMPUTE(bufv, khv) do {                                            \
    const bf16* Ap = Ab + ((bufv) * 2 + (khv)) * 4096;                     \
    const bf16* Bp = Bb + ((bufv) * 2 + (khv)) * 8192;                     \
    bf16x8 af[4], bfr[4];                                                  \
    _Pragma("unroll")                                                      \
    for (int mt = 0; mt < 4; mt++) {                                       \
        const int r = wr * 64 + mt * 16 + l16;                             \
        af[mt] = *(const bf16x8*)&Ap[r * 32 + ((quad ^ ((r >> 1) & 3)) << 3)]; \
    }                                                                      \
    _Pragma("unroll")                                                      \
    for (int nt = 0; nt < 4; nt++) {                                       \
        const int r = wc * 64 + nt * 16 + l16;                             \
        bfr[nt] = *(const bf16x8*)&Bp[r * 32 + ((quad ^ ((r >> 1) & 3)) << 3)]; \
    }                                                                      \
    __builtin_amdgcn_s_setprio(1);                                         \
    _Pragma("unroll")                                                      \
    for (int mt = 0; mt < 4; mt++)                                         \
        _Pragma("unroll")                                                  \
        for (int nt = 0; nt < 4; nt++)                                     \
            acc[mt][nt] = __builtin_amdgcn_mfma_f32_16x16x32_bf16(af[mt], bfr[nt], acc[mt][nt], 0, 0, 0); \
    __builtin_amdgcn_s_setprio(0);                                         \
} while (0)

#define PHASE(bufc, khc, bufs, koff, vm) do {                              \
    STAGE(bufs, khc, koff);                                                \
    VMCNT(vm); wg_barrier();                                               \
    COMPUTE(bufc, khc);                                                    \
} while (0)

    // prologue: tiles 0,1 (phases 0..3), 12 loads in flight
    STAGE(0, 0, 0);
    STAGE(0, 1, 32);
    STAGE(1, 0, 64);
    STAGE(1, 1, 96);
#pragma unroll 1
    for (int t0 = 0; t0 < 12; t0 += 3) {
        const int kb = (t0 + 2) * 64;     // k offset of tile t0+2
        PHASE(0, 0, 2, kb,       12);
        PHASE(0, 1, 2, kb + 32,  12);
        PHASE(1, 0, 0, kb + 64,  12);
        PHASE(1, 1, 0, kb + 96,  12);
        PHASE(2, 0, 1, kb + 128, 12);
        PHASE(2, 1, 1, kb + 160, 12);
    }
    // t = 12 (buf 0): stages tile 14 -> buf 2
    PHASE(0, 0, 2, 896, 12);
    PHASE(0, 1, 2, 928, 12);
    // t = 13 (buf 1): stages tile 15 -> buf 0
    PHASE(1, 0, 0, 960, 12);
    PHASE(1, 1, 0, 992, 12);
    // t = 14 (buf 2): no stage, drain
    VMCNT(9); wg_barrier(); COMPUTE(2, 0);
    VMCNT(6); wg_barrier(); COMPUTE(2, 1);
    // t = 15 (buf 0)
    VMCNT(3); wg_barrier(); COMPUTE(0, 0);
    VMCNT(0); wg_barrier(); COMPUTE(0, 1);
#undef PHASE
#undef STAGE
#undef COMPUTE
}

// ---------------------------------------------------------------------------
// Kernel 1: MFMA QKV projection, pipelined 128x256 tile, fused q/k L2-norm.
// C[8192x3072] = X . W^T; grid 768 blocks (= 3 full waves at 1 block/CU).
// Row-fast block order: XCD = bid%8 = row-panel%8 -> each XCD keeps its 8
// A-panels (2 MB) L2-resident and streams W.
// ---------------------------------------------------------------------------
__global__ __launch_bounds__(512, 2) void qkv_gemm_mfma_kernel(
    const int* __restrict__ flag,
    const bf16* __restrict__ Xws, const bf16* __restrict__ Wws,
    const bf16* __restrict__ Xdir, const bf16* __restrict__ Wdir,
    const float* __restrict__ bias_f,
    bf16* __restrict__ q, bf16* __restrict__ k, bf16* __restrict__ vt)
{
    const bf16* X = (*flag) ? Xws : Xdir;
    const bf16* W = (*flag) ? Wws : Wdir;
    __shared__ bf16 Ab[3 * 2 * 4096];   // 48 KB
    __shared__ bf16 Bb[3 * 2 * 8192];   // 96 KB

    const int bid = blockIdx.x;
    const int by  = bid & 63;           // row panel (fast)
    const int bx  = bid >> 6;           // col panel 0..11
    const int row0 = by * 128;
    const int col0 = bx * 256;

    f32x4 acc[4][4] = {};
    mfma_mainloop_128x256(X, W, row0, col0, Ab, Bb, acc);

    const int tid  = threadIdx.x;
    const int w    = tid >> 6;
    const int lane = tid & 63;
    const int l16  = lane & 15, quad = lane >> 4;
    const int wr   = w >> 2, wc = w & 3;

    const int cbase = col0 + wc * 64;          // wave-uniform, spans one head
    const int part  = cbase >> 10;
    const int h     = (cbase & 1023) >> 6;
    float bias[4];
#pragma unroll
    for (int nt = 0; nt < 4; nt++) bias[nt] = bias_f[cbase + nt * 16 + l16];

    if (part < 2) {
        bf16* dst0 = (part == 0) ? q : k;
#pragma unroll
        for (int mt = 0; mt < 4; mt++) {
#pragma unroll
            for (int rg = 0; rg < 4; rg++) {
                const int r = row0 + wr * 64 + mt * 16 + quad * 4 + rg;
                const int l = r >> 3, nn = r & 7;
                float val[4]; float ss = 0.f;
#pragma unroll
                for (int nt = 0; nt < 4; nt++) {
                    val[nt] = acc[mt][nt][rg] + bias[nt];
                    ss += val[nt] * val[nt];
                }
                ss += __shfl_xor(ss, 1); ss += __shfl_xor(ss, 2);
                ss += __shfl_xor(ss, 4); ss += __shfl_xor(ss, 8);
                const float inv = 1.f / fmaxf(sqrtf(ss), 1e-12f);
                bf16* dp = dst0 + ((size_t)((nn * 16 + h) * 1024 + l)) * 64;
#pragma unroll
                for (int nt = 0; nt < 4; nt++)
                    dp[nt * 16 + l16] = __float2bfloat16(val[nt] * inv);
            }
        }
    } else {
#pragma unroll
        for (int mt = 0; mt < 4; mt++) {
#pragma unroll
            for (int rg = 0; rg < 4; rg++) {
                const int r = row0 + wr * 64 + mt * 16 + quad * 4 + rg;
                const int l = r >> 3, nn = r & 7;
#pragma unroll
                for (int nt = 0; nt < 4; nt++) {
                    const int d = nt * 16 + l16;
                    vt[((size_t)((nn * 16 + h) * 64 + d)) * 1024 + l] =
                        __float2bfloat16(acc[mt][nt][rg] + bias[nt]);
                }
            }
        }
    }
}

// ---------------------------------------------------------------------------
// Kernel 3: MFMA flash attention v2 + XCD swizzle (unchanged).
// ---------------------------------------------------------------------------
__global__ __launch_bounds__(256, 4) void attn_mfma_kernel(
    const bf16* __restrict__ q, const bf16* __restrict__ k,
    const bf16* __restrict__ vt, const float* __restrict__ scale_f,
    bf16* __restrict__ o)
{
    __shared__ bf16 K_lds[64][64];
    __shared__ bf16 Vt_lds[64][64];
    __shared__ bf16 P_lds[4][32][72];
    __shared__ float l_lds[4][32];

    const int bid  = blockIdx.x;
    const int qt   = bid >> 7;         // 0..7  (slow index)
    const int nh   = bid & 127;        // fast index -> XCD = nh & 7
    const int h    = nh & 15;
    const int n    = nh >> 4;
    const int tid  = threadIdx.x;
    const int w    = tid >> 6;
    const int lane = tid & 63;
    const int l16  = lane & 15;
    const int quad = lane >> 4;

    const size_t base = (size_t)nh * (1024 * 64);
    const float ls   = scale_f[4096 + h];
    const float hs   = scale_f[4112 + h];
    const float lsl2 = ls * 1.4426950408889634f;

    bf16x8 qf[2][2];
#pragma unroll
    for (int u = 0; u < 2; u++) {
        const int qrow = qt * 128 + w * 32 + u * 16 + l16;
        const bf16* qp = q + base + (size_t)qrow * 64 + quad * 8;
        qf[u][0] = *(const bf16x8*)qp;
        qf[u][1] = *(const bf16x8*)(qp + 32);
    }

    f32x4 o_acc[2][4] = {};
    float l_part[2] = {0.f, 0.f};

    const int sr = lane >> 3;
    const int sc = lane & 7;

    for (int j0 = 0; j0 < 1024; j0 += 64) {
        __syncthreads();
#pragma unroll
        for (int half = 0; half < 2; half++) {
            const int br  = w * 16 + half * 8;
            const int row = br + sr;
            const int cg  = sc ^ (row & 7);
            async16(k  + base + (size_t)(j0 + row) * 64 + cg * 8, &K_lds[br][0]);
            async16(vt + base + (size_t)row * 1024 + j0 + cg * 8, &Vt_lds[br][0]);
        }
        __syncthreads();

        f32x4 s8[2][4];
#pragma unroll
        for (int s = 0; s < 4; s++) {
            const int krow = s * 16 + l16;
            const int swz  = krow & 7;
            const bf16x8 kf0 = *(const bf16x8*)&K_lds[krow][(quad ^ swz) * 8];
            const bf16x8 kf1 = *(const bf16x8*)&K_lds[krow][((quad + 4) ^ swz) * 8];
#pragma unroll
            for (int u = 0; u < 2; u++) {
                f32x4 a = {};
                a = __builtin_amdgcn_mfma_f32_16x16x32_bf16(kf0, qf[u][0], a, 0, 0, 0);
                a = __builtin_amdgcn_mfma_f32_16x16x32_bf16(kf1, qf[u][1], a, 0, 0, 0);
                s8[u][s] = a;
            }
        }

#pragma unroll
        for (int u = 0; u < 2; u++) {
#pragma unroll
            for (int s = 0; s < 4; s++) {
                union { bf16 b[4]; uint2 uu; } pk;
                float sum = 0.f;
#pragma unroll
                for (int r = 0; r < 4; r++) {
                    const float p = exp2f(fmaf(s8[u][s][r], lsl2, -lsl2));
                    pk.b[r] = __float2bfloat16(p);
                    sum += p;
                }
                l_part[u] += sum;
                *(uint2*)&P_lds[w][u * 16 + l16][s * 16 + quad * 4] = pk.uu;
            }
        }

        bf16x8 pf[2][2];
#pragma unroll
        for (int u = 0; u < 2; u++) {
            pf[u][0] = *(const bf16x8*)&P_lds[w][u * 16 + l16][quad * 8];
            pf[u][1] = *(const bf16x8*)&P_lds[w][u * 16 + l16][32 + quad * 8];
        }
#pragma unroll
        for (int ds = 0; ds < 4; ds++) {
            const int vrow = ds * 16 + l16;
            const int swz  = vrow & 7;
            const bf16x8 vf0 = *(const bf16x8*)&Vt_lds[vrow][(quad ^ swz) * 8];
            const bf16x8 vf1 = *(const bf16x8*)&Vt_lds[vrow][((quad + 4) ^ swz) * 8];
#pragma unroll
            for (int u = 0; u < 2; u++) {
                o_acc[u][ds] = __builtin_amdgcn_mfma_f32_16x16x32_bf16(pf[u][0], vf0, o_acc[u][ds], 0, 0, 0);
                o_acc[u][ds] = __builtin_amdgcn_mfma_f32_16x16x32_bf16(pf[u][1], vf1, o_acc[u][ds], 0, 0, 0);
            }
        }
    }

#pragma unroll
    for (int u = 0; u < 2; u++) {
        float v = l_part[u];
        v += __shfl_xor(v, 16);
        v += __shfl_xor(v, 32);
        l_lds[w][u * 16 + l16] = v;
    }

#pragma unroll
    for (int u = 0; u < 2; u++) {
#pragma unroll
        for (int r = 0; r < 4; r++) {
            const float inv = hs / l_lds[w][u * 16 + quad * 4 + r];
            const int row_l = qt * 128 + w * 32 + u * 16 + quad * 4 + r;
            bf16* dst = o + ((size_t)row_l * 8 + n) * 1024 + h * 64 + l16;
#pragma unroll
            for (int ds = 0; ds < 4; ds++)
                dst[ds * 16] = __float2bfloat16(o_acc[u][ds][r] * inv);
        }
    }
}

// ---------------------------------------------------------------------------
// Kernel 4: MFMA out projection, pipelined 128x256 tile, single launch.
// out[8192x1024] = A . W^T + b; grid 256 blocks (= exactly 1/CU, 1 wave).
// ---------------------------------------------------------------------------
__global__ __launch_bounds__(512, 2) void out_gemm_mfma_kernel(
    const int* __restrict__ flag,
    const bf16* __restrict__ A,
    const bf16* __restrict__ Bws, const bf16* __restrict__ Bdir,
    const float* __restrict__ bias_f,
    float* __restrict__ outf, bf16* __restrict__ outb)
{
    const int f = *flag;
    const bf16* B = f ? Bws : Bdir;
    __shared__ bf16 Ab[3 * 2 * 4096];
    __shared__ bf16 Bb[3 * 2 * 8192];

    const int bid = blockIdx.x;
    const int by  = bid & 63;           // row panel (fast)
    const int bx  = bid >> 6;           // col panel 0..3
    const int row0 = by * 128;
    const int col0 = bx * 256;

    f32x4 acc[4][4] = {};
    mfma_mainloop_128x256(A, B, row0, col0, Ab, Bb, acc);

    const int tid  = threadIdx.x;
    const int w    = tid >> 6;
    const int lane = tid & 63;
    const int l16  = lane & 15, quad = lane >> 4;
    const int wr   = w >> 2, wc = w & 3;

#pragma unroll
    for (int mt = 0; mt < 4; mt++) {
        const int rbase = row0 + wr * 64 + mt * 16 + quad * 4;
#pragma unroll
        for (int nt = 0; nt < 4; nt++) {
            const int c = col0 + wc * 64 + nt * 16 + l16;
            const float bias = bias_f[c];
#pragma unroll
            for (int rg = 0; rg < 4; rg++) {
                const float v = acc[mt][nt][rg] + bias;
                const size_t idx = (size_t)(rbase + rg) * 1024 + c;
                if (f) outf[idx] = v; else outb[idx] = __float2bfloat16(v);
            }
        }
    }
}

// ---------------------------------------------------------------------------
extern "C" void kernel_launch(void* const* d_in, const int* in_sizes, int n_in,
                              void* d_out, int out_size, void* d_ws, size_t ws_size,
                              hipStream_t stream)
{
    const size_t SEG = (size_t)8 * 16 * 1024 * 64;   // 8388608 elems
    bf16* qn  = (bf16*)d_ws;
    bf16* kn  = qn + SEG;
    bf16* vt  = kn + SEG;
    bf16* ow  = vt + SEG;
    bf16* xb  = ow + SEG;                  // bf16 copy of x (fp32 mode)
    bf16* wb  = xb + SEG;                  // bf16 copy of in_proj_weight
    bf16* owb = wb + 3145728;              // bf16 copy of out_w
    float* smallf = (float*)(owb + 1048576);   // 4128 floats
    int*   flag   = (int*)(smallf + 4128);

    detect_kernel<<<1, 256, 0, stream>>>((const unsigned short*)d_in[0], flag);

    prep_kernel<<<4096, 256, 0, stream>>>(flag,
        d_in[0], d_in[1], d_in[5], d_in[2], d_in[6], d_in[3], d_in[4],
        xb, wb, owb, smallf);

    // 1) qkv projection (pipelined MFMA, 128x256 tile) + fused q/k L2-normalize
    qkv_gemm_mfma_kernel<<<dim3(768), 512, 0, stream>>>(
        flag, xb, wb, (const bf16*)d_in[0], (const bf16*)d_in[1], smallf, qn, kn, vt);

    // 2) flash attention v2 (MFMA, fixed-max softmax, XCD-local nh)
    attn_mfma_kernel<<<dim3(128 * 8), 256, 0, stream>>>(qn, kn, vt, smallf, ow);

    // 3) out projection (pipelined MFMA, 128x256 tile), single launch
    out_gemm_mfma_kernel<<<dim3(256), 512, 0, stream>>>(
        flag, ow, owb, (const bf16*)d_in[5], smallf + 3072,
        (float*)d_out, (bf16*)d_out);
}

// Round 3
// 287.976 us; speedup vs baseline: 1.0327x; 1.0252x over previous
//
#include <hip/hip_runtime.h>
#include <hip/hip_bf16.h>

typedef __hip_bfloat16 bf16;
typedef __attribute__((ext_vector_type(8))) short bf16x8;
typedef __attribute__((ext_vector_type(4))) float f32x4;

// Problem constants: x (L=1024, N=8, C=1024), H=16 heads, hd=64
#define LOGIT_MAX 4.6051702f   // log(1/0.01)

__device__ __forceinline__ float4 load4(const float* p) { return *(const float4*)p; }

__device__ __forceinline__ void store4bf(bf16* p, float4 v) {
    union { bf16 b[4]; uint2 u; } t;
    t.b[0] = __float2bfloat16(v.x); t.b[1] = __float2bfloat16(v.y);
    t.b[2] = __float2bfloat16(v.z); t.b[3] = __float2bfloat16(v.w);
    *(uint2*)p = t.u;
}

// async global->LDS, 16B/lane; lds base wave-uniform, lane i -> base + i*16B
__device__ __forceinline__ void async16(const bf16* g, const bf16* lds) {
    __builtin_amdgcn_global_load_lds(
        (const __attribute__((address_space(1))) void*)g,
        (__attribute__((address_space(3))) void*)lds, 16, 0, 0);
}

// ---------------------------------------------------------------------------
// Kernel 0 (merged prep + self-detect): every block redundantly detects the
// input dtype from x[0:4096] exponents (L2-resident after first touch).
// Block 0 additionally publishes the flag for downstream kernels and does the
// small conversions; in fp32 mode all blocks convert x / w_in / out_w -> bf16.
// smallf: [0,3072) in_proj_bias, [3072,4096) out_b,
//         [4096,4112) exp(min(ls,MAX)), [4112,4128) head_scale.
// ---------------------------------------------------------------------------
__global__ __launch_bounds__(256) void prep_kernel(
    const void* __restrict__ x, const void* __restrict__ w_in, const void* __restrict__ out_w,
    const void* __restrict__ b_in, const void* __restrict__ out_b,
    const void* __restrict__ ls, const void* __restrict__ hs,
    bf16* __restrict__ xb, bf16* __restrict__ wb, bf16* __restrict__ owb,
    float* __restrict__ smallf, int* __restrict__ flag)
{
    // --- self-detect (identical semantics to the old detect_kernel) ---
    __shared__ int cnt;
    if (threadIdx.x == 0) cnt = 0;
    __syncthreads();
    {
        const unsigned short* xs = (const unsigned short*)x;
        int c = 0;
        for (int i = threadIdx.x; i < 4096; i += 256) {
            const unsigned e = (xs[i] >> 7) & 0xFF;
            if (e >= 0x90) c++;
        }
        atomicAdd(&cnt, c);
    }
    __syncthreads();
    const int f = (cnt > 64) ? 1 : 0;

    if (blockIdx.x == 0) {
        if (threadIdx.x == 0) *flag = f;
        for (int idx = threadIdx.x; idx < 4128; idx += 256) {
            float v;
            if (f) {
                if (idx < 3072)      v = ((const float*)b_in)[idx];
                else if (idx < 4096) v = ((const float*)out_b)[idx - 3072];
                else if (idx < 4112) v = expf(fminf(((const float*)ls)[idx - 4096], LOGIT_MAX));
                else                 v = ((const float*)hs)[idx - 4112];
            } else {
                if (idx < 3072)      v = __bfloat162float(((const bf16*)b_in)[idx]);
                else if (idx < 4096) v = __bfloat162float(((const bf16*)out_b)[idx - 3072]);
                else if (idx < 4112) v = expf(fminf(__bfloat162float(((const bf16*)ls)[idx - 4096]), LOGIT_MAX));
                else                 v = __bfloat162float(((const bf16*)hs)[idx - 4112]);
            }
            smallf[idx] = v;
        }
    }
    if (f != 1) return;
    const size_t NX = 8388608, NW = 3145728, NO = 1048576;
    const size_t t0   = ((size_t)blockIdx.x * 256 + threadIdx.x) * 4;
    const size_t step = (size_t)gridDim.x * 256 * 4;
    for (size_t i = t0; i < NX; i += step) store4bf(xb + i, load4((const float*)x + i));
    for (size_t i = t0; i < NW; i += step) store4bf(wb + i, load4((const float*)w_in + i));
    for (size_t i = t0; i < NO; i += step) store4bf(owb + i, load4((const float*)out_w + i));
}

// ---------------------------------------------------------------------------
// Kernel 1: MFMA QKV projection, BK=64, fused q/k L2-normalize.
// C[8192x3072] = X . W^T; 128x128 tile, 4 waves 2x2.   (round-0 verified)
// ---------------------------------------------------------------------------
__global__ __launch_bounds__(256, 3) void qkv_gemm_mfma_kernel(
    const int* __restrict__ flag,
    const bf16* __restrict__ Xws, const bf16* __restrict__ Wws,
    const bf16* __restrict__ Xdir, const bf16* __restrict__ Wdir,
    const float* __restrict__ bias_f,
    bf16* __restrict__ q, bf16* __restrict__ k, bf16* __restrict__ vt)
{
    const bf16* X = (*flag) ? Xws : Xdir;
    const bf16* W = (*flag) ? Wws : Wdir;
    __shared__ bf16 A_lds[128 * 64];
    __shared__ bf16 B_lds[128 * 64];
    const int tid  = threadIdx.x;
    const int w    = tid >> 6;
    const int lane = tid & 63;
    const int l16  = lane & 15, quad = lane >> 4;
    const int wm   = w >> 1, wn = w & 1;
    const int row0 = blockIdx.y * 128;
    const int col0 = blockIdx.x * 128;
    const int sr   = lane >> 3, sc = lane & 7;
    const int scg  = sc ^ sr;            // source chunk for swizzled staging

    f32x4 acc[4][4] = {};

    for (int kt = 0; kt < 1024; kt += 64) {
        __syncthreads();
#pragma unroll
        for (int i = 0; i < 4; i++) {
            const int br = w * 32 + i * 8;     // 8 rows per inst, br % 8 == 0
            async16(X + (size_t)(row0 + br + sr) * 1024 + kt + scg * 8, &A_lds[br * 64]);
            async16(W + (size_t)(col0 + br + sr) * 1024 + kt + scg * 8, &B_lds[br * 64]);
        }
        __syncthreads();

#pragma unroll
        for (int kh = 0; kh < 2; kh++) {
            bf16x8 af[4], bf[4];
#pragma unroll
            for (int mt = 0; mt < 4; mt++) {
                const int row = wm * 64 + mt * 16 + l16;
                af[mt] = *(const bf16x8*)&A_lds[row * 64 + (((quad + kh * 4) ^ (row & 7)) * 8)];
            }
#pragma unroll
            for (int nt = 0; nt < 4; nt++) {
                const int row = wn * 64 + nt * 16 + l16;
                bf[nt] = *(const bf16x8*)&B_lds[row * 64 + (((quad + kh * 4) ^ (row & 7)) * 8)];
            }
#pragma unroll
            for (int mt = 0; mt < 4; mt++)
#pragma unroll
                for (int nt = 0; nt < 4; nt++)
                    acc[mt][nt] = __builtin_amdgcn_mfma_f32_16x16x32_bf16(af[mt], bf[nt], acc[mt][nt], 0, 0, 0);
        }
    }

    const int cbase = col0 + wn * 64;          // wave-uniform
    const int part  = cbase >> 10;
    const int h     = (cbase & 1023) >> 6;
    float bias[4];
#pragma unroll
    for (int nt = 0; nt < 4; nt++) bias[nt] = bias_f[cbase + nt * 16 + l16];

    if (part < 2) {
        bf16* dst0 = (part == 0) ? q : k;
#pragma unroll
        for (int mt = 0; mt < 4; mt++) {
#pragma unroll
            for (int rg = 0; rg < 4; rg++) {
                const int r = row0 + wm * 64 + mt * 16 + quad * 4 + rg;
                const int l = r >> 3, nn = r & 7;
                float val[4]; float ss = 0.f;
#pragma unroll
                for (int nt = 0; nt < 4; nt++) {
                    val[nt] = acc[mt][nt][rg] + bias[nt];
                    ss += val[nt] * val[nt];
                }
                ss += __shfl_xor(ss, 1); ss += __shfl_xor(ss, 2);
                ss += __shfl_xor(ss, 4); ss += __shfl_xor(ss, 8);
                const float inv = 1.f / fmaxf(sqrtf(ss), 1e-12f);
                bf16* dp = dst0 + ((size_t)((nn * 16 + h) * 1024 + l)) * 64;
#pragma unroll
                for (int nt = 0; nt < 4; nt++)
                    dp[nt * 16 + l16] = __float2bfloat16(val[nt] * inv);
            }
        }
    } else {
#pragma unroll
        for (int mt = 0; mt < 4; mt++) {
#pragma unroll
            for (int rg = 0; rg < 4; rg++) {
                const int r = row0 + wm * 64 + mt * 16 + quad * 4 + rg;
                const int l = r >> 3, nn = r & 7;
#pragma unroll
                for (int nt = 0; nt < 4; nt++) {
                    const int d = nt * 16 + l16;
                    vt[((size_t)((nn * 16 + h) * 64 + d)) * 1024 + l] =
                        __float2bfloat16(acc[mt][nt][rg] + bias[nt]);
                }
            }
        }
    }
}

// ---------------------------------------------------------------------------
// Kernel 3: MFMA flash attention, 256-row q-tile (8 warps), XCD-local nh.
// bid = qt*128 + nh -> XCD = nh & 7: all 4 q-tiles of one (n,h) on one XCD;
// K/V staging per unit MFMA work is HALVED vs the 128-row version (each
// (n,h)'s K/V tiles re-staged 4x instead of 8x).
// LDS: K 8K + Vt 8K + P 36K + l 1K = 54 KB -> 2 blocks/CU (16 waves).
// ---------------------------------------------------------------------------
__global__ __launch_bounds__(512, 2) void attn_mfma_kernel(
    const bf16* __restrict__ q, const bf16* __restrict__ k,
    const bf16* __restrict__ vt, const float* __restrict__ scale_f,
    bf16* __restrict__ o)
{
    __shared__ bf16 K_lds[64][64];
    __shared__ bf16 Vt_lds[64][64];
    __shared__ bf16 P_lds[8][32][72];
    __shared__ float l_lds[8][32];

    const int bid  = blockIdx.x;
    const int qt   = bid >> 7;         // 0..3  (slow index)
    const int nh   = bid & 127;        // fast index -> XCD = nh & 7
    const int h    = nh & 15;
    const int n    = nh >> 4;
    const int tid  = threadIdx.x;
    const int w    = tid >> 6;         // 0..7
    const int lane = tid & 63;
    const int l16  = lane & 15;
    const int quad = lane >> 4;

    const size_t base = (size_t)nh * (1024 * 64);
    const float ls   = scale_f[4096 + h];
    const float hs   = scale_f[4112 + h];
    const float lsl2 = ls * 1.4426950408889634f;

    bf16x8 qf[2][2];
#pragma unroll
    for (int u = 0; u < 2; u++) {
        const int qrow = qt * 256 + w * 32 + u * 16 + l16;
        const bf16* qp = q + base + (size_t)qrow * 64 + quad * 8;
        qf[u][0] = *(const bf16x8*)qp;
        qf[u][1] = *(const bf16x8*)(qp + 32);
    }

    f32x4 o_acc[2][4] = {};
    float l_part[2] = {0.f, 0.f};

    const int sr = lane >> 3;
    const int sc = lane & 7;

    for (int j0 = 0; j0 < 1024; j0 += 64) {
        __syncthreads();
        {
            const int row = w * 8 + sr;        // warp w stages rows [8w, 8w+8)
            const int cg  = sc ^ (row & 7);
            async16(k  + base + (size_t)(j0 + row) * 64 + cg * 8, &K_lds[w * 8][0]);
            async16(vt + base + (size_t)row * 1024 + j0 + cg * 8, &Vt_lds[w * 8][0]);
        }
        __syncthreads();

        f32x4 s8[2][4];
#pragma unroll
        for (int s = 0; s < 4; s++) {
            const int krow = s * 16 + l16;
            const int swz  = krow & 7;
            const bf16x8 kf0 = *(const bf16x8*)&K_lds[krow][(quad ^ swz) * 8];
            const bf16x8 kf1 = *(const bf16x8*)&K_lds[krow][((quad + 4) ^ swz) * 8];
#pragma unroll
            for (int u = 0; u < 2; u++) {
                f32x4 a = {};
                a = __builtin_amdgcn_mfma_f32_16x16x32_bf16(kf0, qf[u][0], a, 0, 0, 0);
                a = __builtin_amdgcn_mfma_f32_16x16x32_bf16(kf1, qf[u][1], a, 0, 0, 0);
                s8[u][s] = a;
            }
        }

#pragma unroll
        for (int u = 0; u < 2; u++) {
#pragma unroll
            for (int s = 0; s < 4; s++) {
                union { bf16 b[4]; uint2 uu; } pk;
                float sum = 0.f;
#pragma unroll
                for (int r = 0; r < 4; r++) {
                    const float p = exp2f(fmaf(s8[u][s][r], lsl2, -lsl2));
                    pk.b[r] = __float2bfloat16(p);
                    sum += p;
                }
                l_part[u] += sum;
                *(uint2*)&P_lds[w][u * 16 + l16][s * 16 + quad * 4] = pk.uu;
            }
        }

        bf16x8 pf[2][2];
#pragma unroll
        for (int u = 0; u < 2; u++) {
            pf[u][0] = *(const bf16x8*)&P_lds[w][u * 16 + l16][quad * 8];
            pf[u][1] = *(const bf16x8*)&P_lds[w][u * 16 + l16][32 + quad * 8];
        }
#pragma unroll
        for (int ds = 0; ds < 4; ds++) {
            const int vrow = ds * 16 + l16;
            const int swz  = vrow & 7;
            const bf16x8 vf0 = *(const bf16x8*)&Vt_lds[vrow][(quad ^ swz) * 8];
            const bf16x8 vf1 = *(const bf16x8*)&Vt_lds[vrow][((quad + 4) ^ swz) * 8];
#pragma unroll
            for (int u = 0; u < 2; u++) {
                o_acc[u][ds] = __builtin_amdgcn_mfma_f32_16x16x32_bf16(pf[u][0], vf0, o_acc[u][ds], 0, 0, 0);
                o_acc[u][ds] = __builtin_amdgcn_mfma_f32_16x16x32_bf16(pf[u][1], vf1, o_acc[u][ds], 0, 0, 0);
            }
        }
    }

#pragma unroll
    for (int u = 0; u < 2; u++) {
        float v = l_part[u];
        v += __shfl_xor(v, 16);
        v += __shfl_xor(v, 32);
        l_lds[w][u * 16 + l16] = v;
    }

#pragma unroll
    for (int u = 0; u < 2; u++) {
#pragma unroll
        for (int r = 0; r < 4; r++) {
            const float inv = hs / l_lds[w][u * 16 + quad * 4 + r];
            const int row_l = qt * 256 + w * 32 + u * 16 + quad * 4 + r;
            bf16* dst = o + ((size_t)row_l * 8 + n) * 1024 + h * 64 + l16;
#pragma unroll
            for (int ds = 0; ds < 4; ds++)
                dst[ds * 16] = __float2bfloat16(o_acc[u][ds][r] * inv);
        }
    }
}

// ---------------------------------------------------------------------------
// Kernel 4: MFMA out projection, BK=64, single launch (runtime output dtype).
// out[8192x1024] = A . W^T + b.   (round-0 verified)
// ---------------------------------------------------------------------------
__global__ __launch_bounds__(256, 3) void out_gemm_mfma_kernel(
    const int* __restrict__ flag,
    const bf16* __restrict__ A,
    const bf16* __restrict__ Bws, const bf16* __restrict__ Bdir,
    const float* __restrict__ bias_f,
    float* __restrict__ outf, bf16* __restrict__ outb)
{
    const int f = *flag;
    const bf16* B = f ? Bws : Bdir;
    __shared__ bf16 A_lds[128 * 64];
    __shared__ bf16 B_lds[128 * 64];
    const int tid  = threadIdx.x;
    const int w    = tid >> 6;
    const int lane = tid & 63;
    const int l16  = lane & 15, quad = lane >> 4;
    const int wm   = w >> 1, wn = w & 1;
    const int row0 = blockIdx.y * 128;
    const int col0 = blockIdx.x * 128;
    const int sr   = lane >> 3, sc = lane & 7;
    const int scg  = sc ^ sr;

    f32x4 acc[4][4] = {};

    for (int kt = 0; kt < 1024; kt += 64) {
        __syncthreads();
#pragma unroll
        for (int i = 0; i < 4; i++) {
            const int br = w * 32 + i * 8;
            async16(A + (size_t)(row0 + br + sr) * 1024 + kt + scg * 8, &A_lds[br * 64]);
            async16(B + (size_t)(col0 + br + sr) * 1024 + kt + scg * 8, &B_lds[br * 64]);
        }
        __syncthreads();

#pragma unroll
        for (int kh = 0; kh < 2; kh++) {
            bf16x8 af[4], bf[4];
#pragma unroll
            for (int mt = 0; mt < 4; mt++) {
                const int row = wm * 64 + mt * 16 + l16;
                af[mt] = *(const bf16x8*)&A_lds[row * 64 + (((quad + kh * 4) ^ (row & 7)) * 8)];
            }
#pragma unroll
            for (int nt = 0; nt < 4; nt++) {
                const int row = wn * 64 + nt * 16 + l16;
                bf[nt] = *(const bf16x8*)&B_lds[row * 64 + (((quad + kh * 4) ^ (row & 7)) * 8)];
            }
#pragma unroll
            for (int mt = 0; mt < 4; mt++)
#pragma unroll
                for (int nt = 0; nt < 4; nt++)
                    acc[mt][nt] = __builtin_amdgcn_mfma_f32_16x16x32_bf16(af[mt], bf[nt], acc[mt][nt], 0, 0, 0);
        }
    }

#pragma unroll
    for (int mt = 0; mt < 4; mt++) {
        const int rbase = row0 + wm * 64 + mt * 16 + quad * 4;
#pragma unroll
        for (int nt = 0; nt < 4; nt++) {
            const int c = col0 + wn * 64 + nt * 16 + l16;
            const float bias = bias_f[c];
#pragma unroll
            for (int rg = 0; rg < 4; rg++) {
                const float v = acc[mt][nt][rg] + bias;
                const size_t idx = (size_t)(rbase + rg) * 1024 + c;
                if (f) outf[idx] = v; else outb[idx] = __float2bfloat16(v);
            }
        }
    }
}

// ---------------------------------------------------------------------------
extern "C" void kernel_launch(void* const* d_in, const int* in_sizes, int n_in,
                              void* d_out, int out_size, void* d_ws, size_t ws_size,
                              hipStream_t stream)
{
    const size_t SEG = (size_t)8 * 16 * 1024 * 64;   // 8388608 elems
    bf16* qn  = (bf16*)d_ws;
    bf16* kn  = qn + SEG;
    bf16* vt  = kn + SEG;
    bf16* ow  = vt + SEG;
    bf16* xb  = ow + SEG;                  // bf16 copy of x (fp32 mode)
    bf16* wb  = xb + SEG;                  // bf16 copy of in_proj_weight
    bf16* owb = wb + 3145728;              // bf16 copy of out_w
    float* smallf = (float*)(owb + 1048576);   // 4128 floats
    int*   flag   = (int*)(smallf + 4128);

    // 0) prep (self-detecting; one launch)
    prep_kernel<<<4096, 256, 0, stream>>>(
        d_in[0], d_in[1], d_in[5], d_in[2], d_in[6], d_in[3], d_in[4],
        xb, wb, owb, smallf, flag);

    // 1) qkv projection (MFMA, BK=64) + fused q/k L2-normalize
    qkv_gemm_mfma_kernel<<<dim3(3072 / 128, 8192 / 128), 256, 0, stream>>>(
        flag, xb, wb, (const bf16*)d_in[0], (const bf16*)d_in[1], smallf, qn, kn, vt);

    // 2) flash attention (MFMA, fixed-max softmax, 256-row q-tile, XCD-local nh)
    attn_mfma_kernel<<<dim3(128 * 4), 512, 0, stream>>>(qn, kn, vt, smallf, ow);

    // 3) out projection (MFMA, BK=64), single launch
    out_gemm_mfma_kernel<<<dim3(1024 / 128, 8192 / 128), 256, 0, stream>>>(
        flag, ow, owb, (const bf16*)d_in[5], smallf + 3072,
        (float*)d_out, (bf16*)d_out);
}